// Round 4
// baseline (266.533 us; speedup 1.0000x reference)
//
#include <hip/hip_runtime.h>

// Causal cumulative mean: out[b,t,c] = (1/(t+1)) * sum_{s<=t} x[b,s,c]
// x: (B=8, T=4096, C=1024) fp32. Three-kernel chunked scan:
//   A: partial[b][k][c] = sum of x over chunk k (CHUNK=32)  -- 1024 blocks
//   M: exclusive scan of partial along k (tiny, 2048 threads, L2-resident)
//   B: run = scanned partial (1 load) + in-chunk running prefix, out = run*rcp(t+1)
// CHUNK=32 doubles block count vs CHUNK=64 (4 blocks/CU, 16 waves/CU) and the
// pre-scanned partials remove pass B's serial, load-imbalanced prefix loop.

constexpr int B_SZ   = 8;
constexpr int T_SZ   = 4096;
constexpr int C_SZ   = 1024;
constexpr int CHUNK  = 32;
constexpr int NCHUNK = T_SZ / CHUNK;   // 128
constexpr int C4     = C_SZ / 4;       // 256 threads/block

__global__ __launch_bounds__(C4) void cummean_partial(
    const float4* __restrict__ x, float4* __restrict__ part) {
    const int k = blockIdx.x, b = blockIdx.y, c = threadIdx.x;
    const float4* xp = x + (size_t)(b * T_SZ + k * CHUNK) * C4 + c;
    // two independent accumulators for ILP
    float s0x=0.f,s0y=0.f,s0z=0.f,s0w=0.f, s1x=0.f,s1y=0.f,s1z=0.f,s1w=0.f;
#pragma unroll 8
    for (int t = 0; t < CHUNK; t += 2) {
        float4 a = xp[(size_t)t * C4];
        float4 d = xp[(size_t)(t + 1) * C4];
        s0x += a.x; s0y += a.y; s0z += a.z; s0w += a.w;
        s1x += d.x; s1y += d.y; s1z += d.z; s1w += d.w;
    }
    float4 s; s.x = s0x + s1x; s.y = s0y + s1y; s.z = s0z + s1z; s.w = s0w + s1w;
    part[(size_t)(b * NCHUNK + k) * C4 + c] = s;
}

// In-place exclusive scan of part along k, one thread per (b, c-quad).
// Grid: B_SZ blocks of C4 threads -> loads coalesced across c.
__global__ __launch_bounds__(C4) void cummean_scanpart(float4* __restrict__ part) {
    const int b = blockIdx.x, c = threadIdx.x;
    float4* pp = part + (size_t)b * NCHUNK * C4 + c;
    float rx=0.f, ry=0.f, rz=0.f, rw=0.f;
#pragma unroll 4
    for (int k = 0; k < NCHUNK; ++k) {
        float4 v = pp[(size_t)k * C4];
        float4 e; e.x = rx; e.y = ry; e.z = rz; e.w = rw;
        pp[(size_t)k * C4] = e;            // exclusive prefix
        rx += v.x; ry += v.y; rz += v.z; rw += v.w;
    }
}

__global__ __launch_bounds__(C4) void cummean_scan(
    const float4* __restrict__ x, const float4* __restrict__ part,
    float4* __restrict__ out) {
    const int k = blockIdx.x, b = blockIdx.y, c = threadIdx.x;

    float4 run = part[(size_t)(b * NCHUNK + k) * C4 + c];  // exclusive chunk prefix

    const size_t base = (size_t)(b * T_SZ + k * CHUNK) * C4 + c;
    const float4* xp = x + base;
    float4*       op = out + base;
    const int t0 = k * CHUNK;
#pragma unroll 8
    for (int t = 0; t < CHUNK; ++t) {
        float4 v = xp[(size_t)t * C4];
        run.x += v.x; run.y += v.y; run.z += v.z; run.w += v.w;
        const float inv = __builtin_amdgcn_rcpf((float)(t0 + t + 1));  // v_rcp_f32
        float4 o;
        o.x = run.x * inv; o.y = run.y * inv; o.z = run.z * inv; o.w = run.w * inv;
        op[(size_t)t * C4] = o;
    }
}

extern "C" void kernel_launch(void* const* d_in, const int* in_sizes, int n_in,
                              void* d_out, int out_size, void* d_ws, size_t ws_size,
                              hipStream_t stream) {
    const float4* x    = (const float4*)d_in[0];
    float4*       out  = (float4*)d_out;
    float4*       part = (float4*)d_ws;   // B*NCHUNK*C floats = 4 MB

    dim3 grid(NCHUNK, B_SZ);
    cummean_partial<<<grid, C4, 0, stream>>>(x, part);
    cummean_scanpart<<<B_SZ, C4, 0, stream>>>(part);
    cummean_scan<<<grid, C4, 0, stream>>>(x, part, out);
}